// Round 1
// baseline (503.554 us; speedup 1.0000x reference)
//
#include <hip/hip_runtime.h>
#include <stdint.h>

typedef int int32x4 __attribute__((ext_vector_type(4)));

#define M_ROWS 8192
#define K_DIM  4096
#define N_DIM  4096

#define GPTR(p) ((const __attribute__((address_space(1))) unsigned int*)(p))
#define LPTR(p) ((__attribute__((address_space(3))) unsigned int*)(p))

// ---------- shared helper: block-wide absmax over 256 threads ----------
__device__ __forceinline__ float block_absmax_256(float v, float* red) {
#pragma unroll
  for (int off = 32; off > 0; off >>= 1)
    v = fmaxf(v, __shfl_down(v, off, 64));
  const int w = threadIdx.x >> 6;
  if ((threadIdx.x & 63) == 0) red[w] = v;
  __syncthreads();
  return fmaxf(fmaxf(red[0], red[1]), fmaxf(red[2], red[3]));
}

// ---------- 1. per-row quantize x -> int8 + scale ----------
__global__ void quant_x_kernel(const float* __restrict__ x,
                               int8_t* __restrict__ qx,
                               float* __restrict__ sx) {
  __shared__ float red[4];
  const int row = blockIdx.x;
  const int t = threadIdx.x;
  const float* xr = x + (size_t)row * K_DIM;
  float4 v[4];
  float m = 0.0f;
#pragma unroll
  for (int i = 0; i < 4; ++i) {
    v[i] = *(const float4*)(xr + t * 16 + i * 4);
    m = fmaxf(m, fmaxf(fmaxf(fabsf(v[i].x), fabsf(v[i].y)),
                       fmaxf(fabsf(v[i].z), fabsf(v[i].w))));
  }
  float amax = block_absmax_256(m, red);
  float scale = amax / 127.0f;
  if (scale == 0.0f) scale = 1.0f;
  if (t == 0) sx[row] = scale;
  int words[4];
#pragma unroll
  for (int i = 0; i < 4; ++i) {
    float a = fminf(fmaxf(v[i].x / scale, -127.0f), 127.0f);
    float b = fminf(fmaxf(v[i].y / scale, -127.0f), 127.0f);
    float c = fminf(fmaxf(v[i].z / scale, -127.0f), 127.0f);
    float d = fminf(fmaxf(v[i].w / scale, -127.0f), 127.0f);
    int qa = (int)rintf(a), qb = (int)rintf(b), qc = (int)rintf(c), qd = (int)rintf(d);
    words[i] = (qa & 255) | ((qb & 255) << 8) | ((qc & 255) << 16) | ((qd & 255) << 24);
  }
  *(int4*)(qx + (size_t)row * K_DIM + t * 16) =
      make_int4(words[0], words[1], words[2], words[3]);
}

// ---------- 2. per-column absmax of kernel (atomicMax on float bits) ----------
__global__ void colmax_kernel(const float* __restrict__ k,
                              unsigned int* __restrict__ cm) {
  const int c = blockIdx.x * 256 + threadIdx.x;
  const int r0 = blockIdx.y * 128;
  float m = 0.0f;
  for (int i = 0; i < 128; ++i)
    m = fmaxf(m, fabsf(k[(size_t)(r0 + i) * N_DIM + c]));
  atomicMax(&cm[c], __float_as_uint(m));
}

// ---------- 3. finalize scales: s_k from colmax; bias int16 fake-quant ----------
__global__ void finalize_kernel(const float* __restrict__ cm,
                                float* __restrict__ sk,
                                const float* __restrict__ bias,
                                float* __restrict__ bq) {
  __shared__ float red[4];
  const int t = threadIdx.x;
  if (blockIdx.x < 16) {
    const int c = blockIdx.x * 256 + t;
    float s = cm[c] / 127.0f;
    if (s == 0.0f) s = 1.0f;
    sk[c] = s;
  } else {
    float4 v[4];
    float m = 0.0f;
#pragma unroll
    for (int i = 0; i < 4; ++i) {
      v[i] = *(const float4*)(bias + t * 16 + i * 4);
      m = fmaxf(m, fmaxf(fmaxf(fabsf(v[i].x), fabsf(v[i].y)),
                         fmaxf(fabsf(v[i].z), fabsf(v[i].w))));
    }
    float amax = block_absmax_256(m, red);
    float s = amax / 32767.0f;
    if (s == 0.0f) s = 1.0f;
#pragma unroll
    for (int i = 0; i < 4; ++i) {
      float4 o;
      o.x = rintf(fminf(fmaxf(v[i].x / s, -32767.0f), 32767.0f)) * s;
      o.y = rintf(fminf(fmaxf(v[i].y / s, -32767.0f), 32767.0f)) * s;
      o.z = rintf(fminf(fmaxf(v[i].z / s, -32767.0f), 32767.0f)) * s;
      o.w = rintf(fminf(fmaxf(v[i].w / s, -32767.0f), 32767.0f)) * s;
      *(float4*)(bq + t * 16 + i * 4) = o;
    }
  }
}

// ---------- 4. quantize kernel per-col and transpose -> qkT[F][D] int8 ----------
__global__ void quant_kT_kernel(const float* __restrict__ kern,
                                const float* __restrict__ cm,
                                int8_t* __restrict__ qkT) {
  __shared__ int8_t tile[64][68];  // +4 pad breaks write bank conflicts
  const int t = threadIdx.x;
  const int c0 = blockIdx.x * 64;
  const int r0 = blockIdx.y * 64;
  const int tc = t & 63;
  const int tr = t >> 6;  // 0..3
  float s = cm[c0 + tc] / 127.0f;
  if (s == 0.0f) s = 1.0f;
#pragma unroll
  for (int i = 0; i < 16; ++i) {
    const int r = r0 + tr + i * 4;
    float u = kern[(size_t)r * N_DIM + c0 + tc] / s;
    u = fminf(fmaxf(u, -127.0f), 127.0f);
    tile[tc][tr + i * 4] = (int8_t)rintf(u);
  }
  __syncthreads();
  const int cl = t >> 2;
  const int ch = (t & 3) * 16;
  int w4[4];
#pragma unroll
  for (int j = 0; j < 4; ++j) w4[j] = *(const int*)&tile[cl][ch + j * 4];
  *(int4*)(qkT + (size_t)(c0 + cl) * K_DIM + r0 + ch) =
      make_int4(w4[0], w4[1], w4[2], w4[3]);
}

// ---------- 5. int8 GEMM 8192x4096x4096 + scale/bias epilogue ----------
#define BM 128
#define BN 128
#define BK 64

__global__ void gemm_kernel(const int8_t* __restrict__ qx,
                            const int8_t* __restrict__ qkT,
                            const float* __restrict__ sx,
                            const float* __restrict__ sk,
                            const float* __restrict__ bq,
                            float* __restrict__ out) {
  __shared__ int32x4 AsV[512];  // 8 KiB: A tile [128 rows][64 bytes], swizzled slots
  __shared__ int32x4 BsV[512];  // 8 KiB: B tile [128 cols][64 bytes]
  char* As = (char*)AsV;
  char* Bs = (char*)BsV;

  const int t = threadIdx.x;
  const int w = t >> 6;
  const int l = t & 63;
  const int wm = w >> 1, wn = w & 1;
  const int rowBase = blockIdx.y * BM;
  const int colBase = blockIdx.x * BN;

  // XOR swizzle: LDS row r, slot s holds global k-chunk g = s ^ (r&3) ^ ((r>>2)&3).
  // Both the staging fetch chunk and the frag-read slot reduce to the same
  // lane-constant:  sw = (l&3) ^ ((l>>2)&3) ^ (l>>4)
  const int sw = (l & 3) ^ ((l >> 2) & 3) ^ (l >> 4);

  const int8_t* gA = qx  + (size_t)(rowBase + (l >> 2)) * K_DIM + sw * 16;
  const int8_t* gB = qkT + (size_t)(colBase + (l >> 2)) * K_DIM + sw * 16;

  int aoff[4], boff[4];
#pragma unroll
  for (int mt = 0; mt < 4; ++mt)
    aoff[mt] = (wm * 64 + mt * 16 + (l & 15)) * 64 + sw * 16;
#pragma unroll
  for (int nt = 0; nt < 4; ++nt)
    boff[nt] = (wn * 64 + nt * 16 + (l & 15)) * 64 + sw * 16;

  int32x4 zero = {0, 0, 0, 0};
  int32x4 acc[4][4];
#pragma unroll
  for (int mt = 0; mt < 4; ++mt)
#pragma unroll
    for (int nt = 0; nt < 4; ++nt) acc[mt][nt] = zero;

  for (int k0 = 0; k0 < K_DIM; k0 += BK) {
    __syncthreads();  // previous iter's LDS reads done
#pragma unroll
    for (int j = 0; j < 2; ++j) {
      const int chunk = j * 4 + w;  // 0..7 -> 16-row groups
      __builtin_amdgcn_global_load_lds(
          GPTR(gA + (size_t)chunk * 16 * K_DIM + k0),
          LPTR(As + chunk * 1024), 16, 0, 0);
      __builtin_amdgcn_global_load_lds(
          GPTR(gB + (size_t)chunk * 16 * K_DIM + k0),
          LPTR(Bs + chunk * 1024), 16, 0, 0);
    }
    __syncthreads();  // compiler drains vmcnt(0) before barrier

    int32x4 af[4], bf[4];
#pragma unroll
    for (int mt = 0; mt < 4; ++mt) af[mt] = *(const int32x4*)(As + aoff[mt]);
#pragma unroll
    for (int nt = 0; nt < 4; ++nt) bf[nt] = *(const int32x4*)(Bs + boff[nt]);
#pragma unroll
    for (int mt = 0; mt < 4; ++mt)
#pragma unroll
      for (int nt = 0; nt < 4; ++nt)
        acc[mt][nt] = __builtin_amdgcn_mfma_i32_16x16x64_i8(
            af[mt], bf[nt], acc[mt][nt], 0, 0, 0);
  }

  // epilogue: y = acc * sx[row] * sk[col] + bq[col]   (fp32 to d_out)
  const int lr = (l >> 4) * 4;
  const int lc = l & 15;
#pragma unroll
  for (int mt = 0; mt < 4; ++mt) {
    const int r0 = rowBase + wm * 64 + mt * 16 + lr;
    float sxr[4];
#pragma unroll
    for (int r = 0; r < 4; ++r) sxr[r] = sx[r0 + r];
#pragma unroll
    for (int nt = 0; nt < 4; ++nt) {
      const int c = colBase + wn * 64 + nt * 16 + lc;
      const float skc = sk[c];
      const float bqc = bq[c];
#pragma unroll
      for (int r = 0; r < 4; ++r)
        out[(size_t)(r0 + r) * N_DIM + c] =
            (float)acc[mt][nt][r] * (sxr[r] * skc) + bqc;
    }
  }
}

// ---------- 6. per-row int8 requant of output (in place) ----------
__global__ void requant_kernel(float* __restrict__ y) {
  __shared__ float red[4];
  const int row = blockIdx.x;
  const int t = threadIdx.x;
  float* yr = y + (size_t)row * N_DIM;
  float4 v[4];
  float m = 0.0f;
#pragma unroll
  for (int i = 0; i < 4; ++i) {
    v[i] = *(const float4*)(yr + i * 1024 + t * 4);
    m = fmaxf(m, fmaxf(fmaxf(fabsf(v[i].x), fabsf(v[i].y)),
                       fmaxf(fabsf(v[i].z), fabsf(v[i].w))));
  }
  float amax = block_absmax_256(m, red);
  float s = amax / 127.0f;
  if (s == 0.0f) s = 1.0f;
#pragma unroll
  for (int i = 0; i < 4; ++i) {
    float4 o;
    o.x = rintf(fminf(fmaxf(v[i].x / s, -127.0f), 127.0f)) * s;
    o.y = rintf(fminf(fmaxf(v[i].y / s, -127.0f), 127.0f)) * s;
    o.z = rintf(fminf(fmaxf(v[i].z / s, -127.0f), 127.0f)) * s;
    o.w = rintf(fminf(fmaxf(v[i].w / s, -127.0f), 127.0f)) * s;
    *(float4*)(yr + i * 1024 + t * 4) = o;
  }
}

extern "C" void kernel_launch(void* const* d_in, const int* in_sizes, int n_in,
                              void* d_out, int out_size, void* d_ws, size_t ws_size,
                              hipStream_t stream) {
  (void)in_sizes; (void)n_in; (void)out_size; (void)ws_size;
  const float* x    = (const float*)d_in[0];
  const float* kern = (const float*)d_in[1];
  const float* bias = (const float*)d_in[2];
  float* out = (float*)d_out;

  char* w8 = (char*)d_ws;
  int8_t* qx  = (int8_t*)w8;                       // 32 MiB
  int8_t* qkT = (int8_t*)(w8 + 33554432);          // 16 MiB
  float* sx   = (float*)(w8 + 50331648);           // 8192 f
  float* cm   = (float*)(w8 + 50331648 + 32768);   // 4096 f (colmax, needs zero)
  float* sk   = (float*)(w8 + 50331648 + 49152);   // 4096 f
  float* bq   = (float*)(w8 + 50331648 + 65536);   // 4096 f

  hipMemsetAsync(cm, 0, 4096 * sizeof(float), stream);
  quant_x_kernel<<<M_ROWS, 256, 0, stream>>>(x, qx, sx);
  colmax_kernel<<<dim3(16, 32), 256, 0, stream>>>(kern, (unsigned int*)cm);
  finalize_kernel<<<17, 256, 0, stream>>>(cm, sk, bias, bq);
  quant_kT_kernel<<<dim3(64, 64), 256, 0, stream>>>(kern, cm, qkT);
  gemm_kernel<<<dim3(N_DIM / BN, M_ROWS / BM), 256, 0, stream>>>(qx, qkT, sx, sk, bq, out);
  requant_kernel<<<M_ROWS, 256, 0, stream>>>(out);
}

// Round 2
// 469.282 us; speedup vs baseline: 1.0730x; 1.0730x over previous
//
#include <hip/hip_runtime.h>
#include <stdint.h>

typedef int int32x4 __attribute__((ext_vector_type(4)));

#define M_ROWS 8192
#define K_DIM  4096
#define N_DIM  4096

#define GPTR(p) ((const __attribute__((address_space(1))) unsigned int*)(p))
#define LPTR(p) ((__attribute__((address_space(3))) unsigned int*)(p))

// ---------- shared helper: block-wide absmax over 256 threads ----------
__device__ __forceinline__ float block_absmax_256(float v, float* red) {
#pragma unroll
  for (int off = 32; off > 0; off >>= 1)
    v = fmaxf(v, __shfl_down(v, off, 64));
  const int w = threadIdx.x >> 6;
  if ((threadIdx.x & 63) == 0) red[w] = v;
  __syncthreads();
  return fmaxf(fmaxf(red[0], red[1]), fmaxf(red[2], red[3]));
}

// ---------- 1. per-row quantize x -> int8 + scale ----------
__global__ void quant_x_kernel(const float* __restrict__ x,
                               int8_t* __restrict__ qx,
                               float* __restrict__ sx) {
  __shared__ float red[4];
  const int row = blockIdx.x;
  const int t = threadIdx.x;
  const float* xr = x + (size_t)row * K_DIM;
  float4 v[4];
  float m = 0.0f;
#pragma unroll
  for (int i = 0; i < 4; ++i) {
    v[i] = *(const float4*)(xr + t * 16 + i * 4);
    m = fmaxf(m, fmaxf(fmaxf(fabsf(v[i].x), fabsf(v[i].y)),
                       fmaxf(fabsf(v[i].z), fabsf(v[i].w))));
  }
  float amax = block_absmax_256(m, red);
  float scale = amax / 127.0f;
  if (scale == 0.0f) scale = 1.0f;
  if (t == 0) sx[row] = scale;
  int words[4];
#pragma unroll
  for (int i = 0; i < 4; ++i) {
    float a = fminf(fmaxf(v[i].x / scale, -127.0f), 127.0f);
    float b = fminf(fmaxf(v[i].y / scale, -127.0f), 127.0f);
    float c = fminf(fmaxf(v[i].z / scale, -127.0f), 127.0f);
    float d = fminf(fmaxf(v[i].w / scale, -127.0f), 127.0f);
    int qa = (int)rintf(a), qb = (int)rintf(b), qc = (int)rintf(c), qd = (int)rintf(d);
    words[i] = (qa & 255) | ((qb & 255) << 8) | ((qc & 255) << 16) | ((qd & 255) << 24);
  }
  *(int4*)(qx + (size_t)row * K_DIM + t * 16) =
      make_int4(words[0], words[1], words[2], words[3]);
}

// ---------- 2. per-column absmax of kernel (atomicMax on float bits) ----------
__global__ void colmax_kernel(const float* __restrict__ k,
                              unsigned int* __restrict__ cm) {
  const int c = blockIdx.x * 256 + threadIdx.x;
  const int r0 = blockIdx.y * 128;
  float m = 0.0f;
  for (int i = 0; i < 128; ++i)
    m = fmaxf(m, fabsf(k[(size_t)(r0 + i) * N_DIM + c]));
  atomicMax(&cm[c], __float_as_uint(m));
}

// ---------- 3. finalize scales: s_k from colmax; bias int16 fake-quant ----------
__global__ void finalize_kernel(const float* __restrict__ cm,
                                float* __restrict__ sk,
                                const float* __restrict__ bias,
                                float* __restrict__ bq) {
  __shared__ float red[4];
  const int t = threadIdx.x;
  if (blockIdx.x < 16) {
    const int c = blockIdx.x * 256 + t;
    float s = cm[c] / 127.0f;
    if (s == 0.0f) s = 1.0f;
    sk[c] = s;
  } else {
    float4 v[4];
    float m = 0.0f;
#pragma unroll
    for (int i = 0; i < 4; ++i) {
      v[i] = *(const float4*)(bias + t * 16 + i * 4);
      m = fmaxf(m, fmaxf(fmaxf(fabsf(v[i].x), fabsf(v[i].y)),
                         fmaxf(fabsf(v[i].z), fabsf(v[i].w))));
    }
    float amax = block_absmax_256(m, red);
    float s = amax / 32767.0f;
    if (s == 0.0f) s = 1.0f;
#pragma unroll
    for (int i = 0; i < 4; ++i) {
      float4 o;
      o.x = rintf(fminf(fmaxf(v[i].x / s, -32767.0f), 32767.0f)) * s;
      o.y = rintf(fminf(fmaxf(v[i].y / s, -32767.0f), 32767.0f)) * s;
      o.z = rintf(fminf(fmaxf(v[i].z / s, -32767.0f), 32767.0f)) * s;
      o.w = rintf(fminf(fmaxf(v[i].w / s, -32767.0f), 32767.0f)) * s;
      *(float4*)(bq + t * 16 + i * 4) = o;
    }
  }
}

// ---------- 4. quantize kernel per-col and transpose -> qkT[F][D] int8 ----------
// float4 global loads (16 B/lane), LDS transpose, int4 stores.
__global__ void quant_kT_kernel(const float* __restrict__ kern,
                                const float* __restrict__ cm,
                                int8_t* __restrict__ qkT) {
  __shared__ int8_t tile[64][80];  // stride 80: 16-aligned rows, 2-way-read banks
  const int t = threadIdx.x;
  const int c0 = blockIdx.x * 64;
  const int r0 = blockIdx.y * 64;
  const int colg = (t & 15) * 4;   // 4 consecutive columns per thread
  const int row = t >> 4;          // 0..15
  float s[4];
#pragma unroll
  for (int j = 0; j < 4; ++j) {
    float v = cm[c0 + colg + j] / 127.0f;
    s[j] = (v == 0.0f) ? 1.0f : v;
  }
#pragma unroll
  for (int i = 0; i < 4; ++i) {
    const int r = row + i * 16;
    float4 v = *(const float4*)&kern[(size_t)(r0 + r) * N_DIM + c0 + colg];
    tile[colg + 0][r] = (int8_t)rintf(fminf(fmaxf(v.x / s[0], -127.0f), 127.0f));
    tile[colg + 1][r] = (int8_t)rintf(fminf(fmaxf(v.y / s[1], -127.0f), 127.0f));
    tile[colg + 2][r] = (int8_t)rintf(fminf(fmaxf(v.z / s[2], -127.0f), 127.0f));
    tile[colg + 3][r] = (int8_t)rintf(fminf(fmaxf(v.w / s[3], -127.0f), 127.0f));
  }
  __syncthreads();
  const int f = t >> 2;
  const int seg = (t & 3) * 16;
  int4 w = *(const int4*)&tile[f][seg];
  *(int4*)(qkT + (size_t)(c0 + f) * K_DIM + r0 + seg) = w;
}

// ---------- 5. int8 GEMM 8192x4096x4096 + scale/bias epilogue ----------
// BK=128: 32 MFMAs per wave between barrier pairs (vs 16 at BK=64) to cut
// the vmcnt(0)-drain share. LDS 32 KiB -> 5 blocks/CU LDS-limit.
#define BM 128
#define BN 128
#define BK 128

__global__ void gemm_kernel(const int8_t* __restrict__ qx,
                            const int8_t* __restrict__ qkT,
                            const float* __restrict__ sx,
                            const float* __restrict__ sk,
                            const float* __restrict__ bq,
                            float* __restrict__ out) {
  __shared__ int32x4 AsV[1024];  // 16 KiB: A tile [128 rows][128 bytes]
  __shared__ int32x4 BsV[1024];  // 16 KiB: B tile [128 cols][128 bytes]
  char* As = (char*)AsV;
  char* Bs = (char*)BsV;

  const int t = threadIdx.x;
  const int w = t >> 6;
  const int l = t & 63;
  const int wm = w >> 1, wn = w & 1;
  const int rowBase = blockIdx.y * BM;
  const int colBase = blockIdx.x * BN;

  // XOR swizzle, 8 slots of 16 B per 128-B row: global k-chunk g lives at
  // LDS slot g ^ (row & 7).
  // Staging: lane l writes LDS base + l*16 (wave-uniform-base DMA constraint)
  //   -> row l>>3, slot l&7 -> fetches global chunk (l&7)^(l>>3).
  const int8_t* gA = qx  + (size_t)(rowBase + (l >> 3)) * K_DIM
                         + (((l & 7) ^ (l >> 3)) * 16);
  const int8_t* gB = qkT + (size_t)(colBase + (l >> 3)) * K_DIM
                         + (((l & 7) ^ (l >> 3)) * 16);

  // Frag reads: row & 7 == l & 7 for all frag rows (bases are multiples of 8).
  int arow[4], brow[4], soff[2];
#pragma unroll
  for (int mt = 0; mt < 4; ++mt)
    arow[mt] = (wm * 64 + mt * 16 + (l & 15)) * 128;
#pragma unroll
  for (int nt = 0; nt < 4; ++nt)
    brow[nt] = (wn * 64 + nt * 16 + (l & 15)) * 128;
#pragma unroll
  for (int s = 0; s < 2; ++s)
    soff[s] = ((s * 4 + (l >> 4)) ^ (l & 7)) * 16;

  int32x4 zero = {0, 0, 0, 0};
  int32x4 acc[4][4];
#pragma unroll
  for (int mt = 0; mt < 4; ++mt)
#pragma unroll
    for (int nt = 0; nt < 4; ++nt) acc[mt][nt] = zero;

  for (int k0 = 0; k0 < K_DIM; k0 += BK) {
    __syncthreads();  // previous iter's LDS reads done
#pragma unroll
    for (int j = 0; j < 4; ++j) {
      const int ca = j * 4 + w;  // 16 chunks of 8 rows x 128 B
      __builtin_amdgcn_global_load_lds(
          GPTR(gA + (size_t)ca * 8 * K_DIM + k0),
          LPTR(As + ca * 1024), 16, 0, 0);
      __builtin_amdgcn_global_load_lds(
          GPTR(gB + (size_t)ca * 8 * K_DIM + k0),
          LPTR(Bs + ca * 1024), 16, 0, 0);
    }
    __syncthreads();  // drain vmcnt(0) before reads

#pragma unroll
    for (int s = 0; s < 2; ++s) {
      int32x4 af[4], bf[4];
#pragma unroll
      for (int mt = 0; mt < 4; ++mt)
        af[mt] = *(const int32x4*)(As + arow[mt] + soff[s]);
#pragma unroll
      for (int nt = 0; nt < 4; ++nt)
        bf[nt] = *(const int32x4*)(Bs + brow[nt] + soff[s]);
#pragma unroll
      for (int mt = 0; mt < 4; ++mt)
#pragma unroll
        for (int nt = 0; nt < 4; ++nt)
          acc[mt][nt] = __builtin_amdgcn_mfma_i32_16x16x64_i8(
              af[mt], bf[nt], acc[mt][nt], 0, 0, 0);
    }
  }

  // epilogue: y = acc * sx[row] * sk[col] + bq[col]   (fp32 to d_out)
  const int lr = (l >> 4) * 4;
  const int lc = l & 15;
#pragma unroll
  for (int mt = 0; mt < 4; ++mt) {
    const int r0 = rowBase + wm * 64 + mt * 16 + lr;
    float sxr[4];
#pragma unroll
    for (int r = 0; r < 4; ++r) sxr[r] = sx[r0 + r];
#pragma unroll
    for (int nt = 0; nt < 4; ++nt) {
      const int c = colBase + wn * 64 + nt * 16 + lc;
      const float skc = sk[c];
      const float bqc = bq[c];
#pragma unroll
      for (int r = 0; r < 4; ++r)
        out[(size_t)(r0 + r) * N_DIM + c] =
            (float)acc[mt][nt][r] * (sxr[r] * skc) + bqc;
    }
  }
}

// ---------- 6. per-row int8 requant of output (in place) ----------
__global__ void requant_kernel(float* __restrict__ y) {
  __shared__ float red[4];
  const int row = blockIdx.x;
  const int t = threadIdx.x;
  float* yr = y + (size_t)row * N_DIM;
  float4 v[4];
  float m = 0.0f;
#pragma unroll
  for (int i = 0; i < 4; ++i) {
    v[i] = *(const float4*)(yr + i * 1024 + t * 4);
    m = fmaxf(m, fmaxf(fmaxf(fabsf(v[i].x), fabsf(v[i].y)),
                       fmaxf(fabsf(v[i].z), fabsf(v[i].w))));
  }
  float amax = block_absmax_256(m, red);
  float s = amax / 127.0f;
  if (s == 0.0f) s = 1.0f;
#pragma unroll
  for (int i = 0; i < 4; ++i) {
    float4 o;
    o.x = rintf(fminf(fmaxf(v[i].x / s, -127.0f), 127.0f)) * s;
    o.y = rintf(fminf(fmaxf(v[i].y / s, -127.0f), 127.0f)) * s;
    o.z = rintf(fminf(fmaxf(v[i].z / s, -127.0f), 127.0f)) * s;
    o.w = rintf(fminf(fmaxf(v[i].w / s, -127.0f), 127.0f)) * s;
    *(float4*)(yr + i * 1024 + t * 4) = o;
  }
}

extern "C" void kernel_launch(void* const* d_in, const int* in_sizes, int n_in,
                              void* d_out, int out_size, void* d_ws, size_t ws_size,
                              hipStream_t stream) {
  (void)in_sizes; (void)n_in; (void)out_size; (void)ws_size;
  const float* x    = (const float*)d_in[0];
  const float* kern = (const float*)d_in[1];
  const float* bias = (const float*)d_in[2];
  float* out = (float*)d_out;

  char* w8 = (char*)d_ws;
  int8_t* qx  = (int8_t*)w8;                       // 32 MiB
  int8_t* qkT = (int8_t*)(w8 + 33554432);          // 16 MiB
  float* sx   = (float*)(w8 + 50331648);           // 8192 f
  float* cm   = (float*)(w8 + 50331648 + 32768);   // 4096 f (colmax, needs zero)
  float* sk   = (float*)(w8 + 50331648 + 49152);   // 4096 f
  float* bq   = (float*)(w8 + 50331648 + 65536);   // 4096 f

  hipMemsetAsync(cm, 0, 4096 * sizeof(float), stream);
  quant_x_kernel<<<M_ROWS, 256, 0, stream>>>(x, qx, sx);
  colmax_kernel<<<dim3(16, 32), 256, 0, stream>>>(kern, (unsigned int*)cm);
  finalize_kernel<<<17, 256, 0, stream>>>(cm, sk, bias, bq);
  quant_kT_kernel<<<dim3(64, 64), 256, 0, stream>>>(kern, cm, qkT);
  gemm_kernel<<<dim3(N_DIM / BN, M_ROWS / BM), 256, 0, stream>>>(qx, qkT, sx, sk, bq, out);
  requant_kernel<<<M_ROWS, 256, 0, stream>>>(out);
}